// Round 10
// baseline (163.163 us; speedup 1.0000x reference)
//
#include <hip/hip_runtime.h>
#include <hip/hip_bf16.h>
#include <math.h>

#define DIM 192
#define NHD 6
#define HD 32
#define KSZ 7
#define HID 768
#define IMH 128
#define IMW 128
#define NPIX (IMH*IMW)
#define WIN 14
#define KPAD 40

typedef __attribute__((ext_vector_type(8))) short short8;
typedef __attribute__((ext_vector_type(4))) float f32x4;

#define LDS_SYNC() do { \
    asm volatile("s_waitcnt lgkmcnt(0)" ::: "memory"); \
    __builtin_amdgcn_sched_barrier(0); \
    __builtin_amdgcn_s_barrier(); } while (0)

// ---------------- qkv weight fp32->bf16 (108 blocks; wp/wf1/wf2 ride in the attn launch) ----------------
__global__ __launch_bounds__(256) void cvt_w(
    const float* __restrict__ qw, __hip_bfloat16* __restrict__ dq)
{
    int idx = blockIdx.x * 1024 + threadIdx.x * 4;
    float4 v4 = *(const float4*)(qw + idx);
    union { ushort4 u; __hip_bfloat16 h[4]; } o;
    o.h[0] = __float2bfloat16(v4.x); o.h[1] = __float2bfloat16(v4.y);
    o.h[2] = __float2bfloat16(v4.z); o.h[3] = __float2bfloat16(v4.w);
    *(ushort4*)&dq[idx] = o.u;
}

__device__ __forceinline__ void gl_lds16(const void* g, void* l) {
    __builtin_amdgcn_global_load_lds(
        (const __attribute__((address_space(1))) void*)g,
        (__attribute__((address_space(3))) void*)l, 16, 0, 0);
}

__device__ __forceinline__ short8 cvt8(float4 a, float4 b) {
    union { short8 v; __hip_bfloat16 h[8]; } u;
    u.h[0] = __float2bfloat16(a.x); u.h[1] = __float2bfloat16(a.y);
    u.h[2] = __float2bfloat16(a.z); u.h[3] = __float2bfloat16(a.w);
    u.h[4] = __float2bfloat16(b.x); u.h[5] = __float2bfloat16(b.y);
    u.h[6] = __float2bfloat16(b.z); u.h[7] = __float2bfloat16(b.w);
    return u.v;
}

// ---- 1024-thread staging: 64 rows x 192 K (1536 slots of 16B), 96 slots/wave,
// exactly 2 VMEM issues per wave (2nd exec-masked to 32 lanes) -> uniform vmcnt.
__device__ __forceinline__ void stage_rows(const __hip_bfloat16* __restrict__ src,
                                           char* ldsbase, int wave, int lane) {
    int c0 = wave * 96 + lane;
    int r0 = c0 / 24, k0 = c0 - r0 * 24;
    gl_lds16(src + (size_t)r0 * DIM + ((k0 ^ (r0 & 7)) * 8), ldsbase + (wave * 96) * 16);
    int c1 = wave * 96 + 64 + (lane & 31);
    int r1 = c1 / 24, k1 = c1 - r1 * 24;
    if (lane < 32)
        gl_lds16(src + (size_t)r1 * DIM + ((k1 ^ (r1 & 7)) * 8), ldsbase + (wave * 96 + 64) * 16);
}
// ---- FC2 weight chunk: 192 n-rows x 64 K (8 slots/row), same 96-slot/wave split
__device__ __forceinline__ void stage_w2(const __hip_bfloat16* __restrict__ W2, int ch,
                                         char* ldsbase, int wave, int lane) {
    int i0 = wave * 96 + lane;
    int r0 = i0 >> 3, o0 = i0 & 7;
    gl_lds16(W2 + (size_t)r0 * HID + ch * 64 + ((o0 ^ (r0 & 7)) * 8), ldsbase + (wave * 96) * 16);
    int i1 = wave * 96 + 64 + (lane & 31);
    int r1 = i1 >> 3, o1 = i1 & 7;
    if (lane < 32)
        gl_lds16(W2 + (size_t)r1 * HID + ch * 64 + ((o1 ^ (r1 & 7)) * 8), ldsbase + (wave * 96 + 64) * 16);
}

// ---------------- QKV GEMM with fused LN1 (unchanged from r8) ----------------
__global__ __launch_bounds__(256, 4) void qkv_ln_gemm(
    const float* __restrict__ x, const float* __restrict__ lnw, const float* __restrict__ lnb,
    const __hip_bfloat16* __restrict__ W, const float* __restrict__ bias,
    __hip_bfloat16* __restrict__ qb, __hip_bfloat16* __restrict__ kb, __hip_bfloat16* __restrict__ vb)
{
    __shared__ __hip_bfloat16 As[32 * 192];   // 12 KB
    __shared__ __hip_bfloat16 Ws[64 * 192];   // 24 KB (single buffer)
    int tid = threadIdx.x;
    int wave = tid >> 6, lane = tid & 63;
    int q = lane >> 4, col = lane & 15;
    int wm = (wave >> 1) * 16, wn = (wave & 1) * 32;
    int m0 = blockIdx.x * 32;

    auto stageW = [&](int ch) {
        #pragma unroll
        for (int i = 0; i < 6; i++) {
            int c = i * 256 + tid;
            int r = c / 24, kc = c - r * 24;
            gl_lds16(W + (size_t)(ch * 64 + r) * DIM + ((kc ^ (r & 7)) * 8),
                     (char*)&Ws[0] + (i * 256 + wave * 64) * 16);
        }
    };

    stageW(0);

    {
        int row = tid >> 3, sub = tid & 7;
        const float4* xr = (const float4*)(x + (size_t)(m0 + row) * DIM + sub * 24);
        float4 xa[6];
        float s = 0.f;
        #pragma unroll
        for (int i = 0; i < 6; i++) {
            xa[i] = xr[i];
            s += xa[i].x + xa[i].y + xa[i].z + xa[i].w;
        }
        s += __shfl_xor(s, 1); s += __shfl_xor(s, 2); s += __shfl_xor(s, 4);
        float mu = s * (1.0f / DIM);
        float qs = 0.f;
        #pragma unroll
        for (int i = 0; i < 6; i++) {
            float a = xa[i].x - mu, b = xa[i].y - mu, c = xa[i].z - mu, d = xa[i].w - mu;
            qs += a * a + b * b + c * c + d * d;
        }
        qs += __shfl_xor(qs, 1); qs += __shfl_xor(qs, 2); qs += __shfl_xor(qs, 4);
        float rstd = rsqrtf(qs * (1.0f / DIM) + 1e-5f);
        const float4* wv = (const float4*)(lnw + sub * 24);
        const float4* bv = (const float4*)(lnb + sub * 24);
        #pragma unroll
        for (int j = 0; j < 3; j++) {
            float4 v0 = xa[j * 2], v1 = xa[j * 2 + 1];
            float4 w0 = wv[j * 2], w1 = wv[j * 2 + 1];
            float4 b0 = bv[j * 2], b1 = bv[j * 2 + 1];
            float4 o0, o1;
            o0.x = (v0.x - mu) * rstd * w0.x + b0.x;
            o0.y = (v0.y - mu) * rstd * w0.y + b0.y;
            o0.z = (v0.z - mu) * rstd * w0.z + b0.z;
            o0.w = (v0.w - mu) * rstd * w0.w + b0.w;
            o1.x = (v1.x - mu) * rstd * w1.x + b1.x;
            o1.y = (v1.y - mu) * rstd * w1.y + b1.y;
            o1.z = (v1.z - mu) * rstd * w1.z + b1.z;
            o1.w = (v1.w - mu) * rstd * w1.w + b1.w;
            int oct = sub * 3 + j;
            *(short8*)&As[row * 192 + ((oct ^ (row & 7)) * 8)] = cvt8(o0, o1);
        }
    }
    asm volatile("s_waitcnt vmcnt(0) lgkmcnt(0)" ::: "memory");
    __builtin_amdgcn_sched_barrier(0);
    __builtin_amdgcn_s_barrier();

    short8 af[6];
    {
        int rA = wm + col;
        #pragma unroll
        for (int ks = 0; ks < 6; ks++)
            af[ks] = *(const short8*)&As[rA * 192 + (((ks * 4 + q) ^ (rA & 7)) * 8)];
    }

    for (int ch = 0; ch < 9; ch++) {
        f32x4 acc[2] = {};
        #pragma unroll
        for (int ks = 0; ks < 6; ks++) {
            #pragma unroll
            for (int ni = 0; ni < 2; ni++) {
                int rB = wn + ni * 16 + col;
                short8 bf = *(const short8*)&Ws[rB * 192 + (((ks * 4 + q) ^ (rB & 7)) * 8)];
                acc[ni] = __builtin_amdgcn_mfma_f32_16x16x32_bf16(af[ks], bf, acc[ni], 0, 0, 0);
            }
        }
        asm volatile("s_waitcnt lgkmcnt(0)" ::: "memory");
        __builtin_amdgcn_sched_barrier(0);
        __builtin_amdgcn_s_barrier();
        if (ch < 8) stageW(ch + 1);
        #pragma unroll
        for (int ni = 0; ni < 2; ni++) {
            int n = ch * 64 + wn + ni * 16 + col;
            float bi = bias[n];
            int h18 = n >> 5;
            int sel = h18 / 6;
            int head = h18 - sel * 6;
            #pragma unroll
            for (int r4 = 0; r4 < 4; r4++) {
                int m = m0 + wm + q * 4 + r4;
                float v = acc[ni][r4] + bi;
                size_t idx = ((size_t)head * NPIX + m) * 32 + (n & 31);
                if (sel == 0)      qb[idx] = __float2bfloat16(v * 0.17677669529663687f);
                else if (sel == 1) kb[idx] = __float2bfloat16(v);
                else               vb[idx] = __float2bfloat16(v);
            }
        }
        if (ch < 8) {
            asm volatile("s_waitcnt vmcnt(8)" ::: "memory");
            __builtin_amdgcn_s_barrier();
        }
    }
}

// ---------------- fused tail v3: proj + LN2 + INTERLEAVED FC1/FC2 (12 phases) ----------------
// 64 rows/block, grid=256, 16 waves. Per chunk t: {vmcnt(0)+bar; prefetch W1[t+1],W2c[t+1];
// FC1 6 MFMA -> gelu -> Ms2[t&1] (8KB hot dbuf); lgkm+bar; FC2 6 MFMA accumulate}.
// Halves MLP sync-points vs split loops; FC2 k-order unchanged -> bit-identical output.
__global__ __launch_bounds__(1024, 4) void tail_fused(
    const __hip_bfloat16* __restrict__ A, const __hip_bfloat16* __restrict__ Wp,
    const float* __restrict__ pb, const float* __restrict__ resid,
    const float* __restrict__ gamma1, const float* __restrict__ ln2w, const float* __restrict__ ln2b,
    const __hip_bfloat16* __restrict__ W1, const float* __restrict__ b1,
    const __hip_bfloat16* __restrict__ W2, const float* __restrict__ b2,
    const float* __restrict__ gamma2, const int* __restrict__ quality,
    float* __restrict__ outf)
{
    __shared__ __hip_bfloat16 Hs[64 * 192];        // 24 KB: attn A-tile, then LN2(h)
    __shared__ __hip_bfloat16 W1b[2][64 * 192];    // 48 KB
    __shared__ __hip_bfloat16 W2b[2][192 * 64];    // 48 KB
    __shared__ __hip_bfloat16 Ms2[2][64 * 64];     // 16 KB gelu chunk, dbuf
    __shared__ float lnred[4][64][2];              // 2 KB      (total 138 KB)

    int tid = threadIdx.x;
    int wave = tid >> 6, lane = tid & 63;
    int q = lane >> 4, col = lane & 15;
    int wm = (wave >> 2) * 16, wq4 = wave & 3;
    int m0 = blockIdx.x * 64;
    int s = quality[0] - 1;

    // prologue: A-tile + proj chunks 0,1 in flight
    stage_rows(A + (size_t)m0 * DIM, (char*)Hs, wave, lane);
    stage_rows(Wp, (char*)&W1b[0][0], wave, lane);
    stage_rows(Wp + 64 * DIM, (char*)&W1b[1][0], wave, lane);
    asm volatile("s_waitcnt vmcnt(2)" ::: "memory");   // Hs + Wp0 landed (Wp1 in flight)
    __builtin_amdgcn_s_barrier();

    short8 afp[6];
    {
        int rA = wm + col;
        #pragma unroll
        for (int ks = 0; ks < 6; ks++)
            afp[ks] = *(const short8*)&Hs[rA * 192 + (((ks * 4 + q) ^ (rA & 7)) * 8)];
    }

    float v[3][4];
    float sm[4] = {}, sq[4] = {};
    auto proj_chunk = [&](int ch, const __hip_bfloat16* wsb) {
        f32x4 pacc = {};
        int rB = wq4 * 16 + col;
        #pragma unroll
        for (int ks = 0; ks < 6; ks++) {
            short8 bf = *(const short8*)&wsb[rB * 192 + (((ks * 4 + q) ^ (rB & 7)) * 8)];
            pacc = __builtin_amdgcn_mfma_f32_16x16x32_bf16(afp[ks], bf, pacc, 0, 0, 0);
        }
        int n = ch * 64 + wq4 * 16 + col;
        float bi = pb[n];
        float g = fabsf(gamma1[s * DIM + n]);
        #pragma unroll
        for (int r = 0; r < 4; r++) {
            int m = m0 + wm + q * 4 + r;
            v[ch][r] = resid[(size_t)m * DIM + n] + g * (pacc[r] + bi);
            sm[r] += v[ch][r]; sq[r] += v[ch][r] * v[ch][r];
        }
    };

    proj_chunk(0, &W1b[0][0]);
    __builtin_amdgcn_s_barrier();
    stage_rows(Wp + 128 * DIM, (char*)&W1b[0][0], wave, lane);   // Wp2
    stage_w2(W2, 0, (char*)&W2b[0][0], wave, lane);              // W2c[0] (after Wp2: FIFO)
    asm volatile("s_waitcnt vmcnt(4)" ::: "memory");             // retires Wp1
    __builtin_amdgcn_s_barrier();
    proj_chunk(1, &W1b[1][0]);
    __builtin_amdgcn_s_barrier();
    stage_rows(W1, (char*)&W1b[1][0], wave, lane);               // W1[0]
    asm volatile("s_waitcnt vmcnt(4)" ::: "memory");             // retires Wp2 (W2c0,W1_0 fly)
    __builtin_amdgcn_s_barrier();
    proj_chunk(2, &W1b[0][0]);

    // ---- LN2 junction ----
    #pragma unroll
    for (int off = 1; off <= 8; off <<= 1)
        #pragma unroll
        for (int r = 0; r < 4; r++) {
            sm[r] += __shfl_xor(sm[r], off);
            sq[r] += __shfl_xor(sq[r], off);
        }
    if (col == 0) {
        #pragma unroll
        for (int r = 0; r < 4; r++) {
            lnred[wq4][wm + q * 4 + r][0] = sm[r];
            lnred[wq4][wm + q * 4 + r][1] = sq[r];
        }
    }
    LDS_SYNC();
    float mu[4], rstd[4];
    #pragma unroll
    for (int r = 0; r < 4; r++) {
        int ml = wm + q * 4 + r;
        float smt = lnred[0][ml][0] + lnred[1][ml][0] + lnred[2][ml][0] + lnred[3][ml][0];
        float sqt = lnred[0][ml][1] + lnred[1][ml][1] + lnred[2][ml][1] + lnred[3][ml][1];
        mu[r] = smt * (1.0f / DIM);
        float var = sqt * (1.0f / DIM) - mu[r] * mu[r];
        rstd[r] = rsqrtf(var + 1e-5f);
    }
    #pragma unroll
    for (int ch = 0; ch < 3; ch++) {
        int n = ch * 64 + wq4 * 16 + col;
        float lw = ln2w[n], lb = ln2b[n];
        #pragma unroll
        for (int r = 0; r < 4; r++) {
            int ml = wm + q * 4 + r;
            Hs[ml * 192 + (((n >> 3) ^ (ml & 7)) * 8) + (n & 7)] =
                __float2bfloat16((v[ch][r] - mu[r]) * rstd[r] * lw + lb);
        }
    }
    LDS_SYNC();
    short8 af1[6];
    {
        int rowA = wm + col;
        #pragma unroll
        for (int ks = 0; ks < 6; ks++)
            af1[ks] = *(const short8*)&Hs[rowA * 192 + (((ks * 4 + q) ^ (rowA & 7)) * 8)];
    }
    // Hs never overwritten again; Ms2 is separate -> no extra sync needed.

    // ---- interleaved FC1+FC2, 12 chunks ----
    f32x4 acc2[3] = {};
    for (int t = 0; t < 12; t++) {
        asm volatile("s_waitcnt vmcnt(0)" ::: "memory");   // W1[t], W2c[t] resident
        __builtin_amdgcn_s_barrier();                       // (A): prior reads done too
        if (t < 11) {
            stage_rows(W1 + (size_t)(t + 1) * 64 * DIM, (char*)&W1b[t & 1][0], wave, lane);
            stage_w2(W2, t + 1, (char*)&W2b[(t + 1) & 1][0], wave, lane);
        }
        // FC1 chunk t
        const __hip_bfloat16* w1p = &W1b[(t + 1) & 1][0];
        f32x4 a1 = {};
        int rB = wq4 * 16 + col;
        #pragma unroll
        for (int ks = 0; ks < 6; ks++) {
            short8 bf = *(const short8*)&w1p[rB * 192 + (((ks * 4 + q) ^ (rB & 7)) * 8)];
            a1 = __builtin_amdgcn_mfma_f32_16x16x32_bf16(af1[ks], bf, a1, 0, 0, 0);
        }
        int nl = wq4 * 16 + col;
        int n = t * 64 + nl;
        float bi = b1[n];
        #pragma unroll
        for (int r4 = 0; r4 < 4; r4++) {
            int row = wm + q * 4 + r4;
            float vv = a1[r4] + bi;
            float u = 0.7978845608f * (vv + 0.044715f * vv * vv * vv);
            float tt = 1.f - 2.f / (__expf(2.f * u) + 1.f);
            vv = 0.5f * vv * (1.f + tt);
            Ms2[t & 1][row * 64 + (((nl >> 3) ^ (row & 7)) << 3) + (nl & 7)] =
                __float2bfloat16(vv);
        }
        asm volatile("s_waitcnt lgkmcnt(0)" ::: "memory");
        __builtin_amdgcn_sched_barrier(0);
        __builtin_amdgcn_s_barrier();                       // (B): Ms2[t&1] visible
        // FC2 partial chunk t
        const __hip_bfloat16* w2p = &W2b[t & 1][0];
        int rowA = wm + col;
        #pragma unroll
        for (int ks = 0; ks < 2; ks++) {
            int oct = ks * 4 + q;
            short8 a2 = *(const short8*)&Ms2[t & 1][rowA * 64 + ((oct ^ (rowA & 7)) << 3)];
            #pragma unroll
            for (int f = 0; f < 3; f++) {
                int rB2 = f * 64 + wq4 * 16 + col;
                short8 bf2 = *(const short8*)&w2p[rB2 * 64 + (((ks * 4 + q) ^ (rB2 & 7)) * 8)];
                acc2[f] = __builtin_amdgcn_mfma_f32_16x16x32_bf16(a2, bf2, acc2[f], 0, 0, 0);
            }
        }
    }

    // ---- final: out = v + |g2|*(fc2+b2)
    #pragma unroll
    for (int f = 0; f < 3; f++) {
        int n = f * 64 + wq4 * 16 + col;
        float g = fabsf(gamma2[s * DIM + n]);
        float bi = b2[n];
        #pragma unroll
        for (int r4 = 0; r4 < 4; r4++) {
            int m = m0 + wm + q * 4 + r4;
            outf[(size_t)m * DIM + n] = v[f][r4] + g * (acc2[f][r4] + bi);
        }
    }
}

// ---------------- MFMA neighborhood attention, 3 blocks/CU (unchanged from r8) ----------------
__global__ __launch_bounds__(256, 3) void attn_mfma(
    const __hip_bfloat16* __restrict__ qbuf, const __hip_bfloat16* __restrict__ kbuf,
    const __hip_bfloat16* __restrict__ vbuf, const float* __restrict__ rpb,
    __hip_bfloat16* __restrict__ out,
    const float* __restrict__ pw, const float* __restrict__ f1w, const float* __restrict__ f2w,
    __hip_bfloat16* __restrict__ dp, __hip_bfloat16* __restrict__ df1, __hip_bfloat16* __restrict__ df2)
{
    if (blockIdx.x >= 256) {
        if (blockIdx.y != 0) return;
        int blk = blockIdx.x - 256, t = threadIdx.x;
        const float* s; __hip_bfloat16* d; int base;
        if (blk < 36)       { s = pw;  d = dp;  base = blk * 1024; }
        else if (blk < 180) { s = f1w; d = df1; base = (blk - 36) * 1024; }
        else                { s = f2w; d = df2; base = (blk - 180) * 1024; }
        int idx = base + t * 4;
        float4 v4 = *(const float4*)(s + idx);
        union { ushort4 u; __hip_bfloat16 h[4]; } o;
        o.h[0] = __float2bfloat16(v4.x); o.h[1] = __float2bfloat16(v4.y);
        o.h[2] = __float2bfloat16(v4.z); o.h[3] = __float2bfloat16(v4.w);
        *(ushort4*)&d[idx] = o.u;
        return;
    }

    __shared__ __hip_bfloat16 Ks[208 * 40];
    __shared__ __hip_bfloat16 Vt[32 * 228];
    __shared__ __hip_bfloat16 Ps[4][16 * 136];
    __shared__ float rpbs[169];

    int head = blockIdx.y, tile = blockIdx.x;
    int ti0 = (tile >> 4) * 8, tj0 = (tile & 15) * 8;
    int wi0 = ti0 - 3; wi0 = wi0 < 0 ? 0 : (wi0 > IMH - WIN ? IMH - WIN : wi0);
    int wj0 = tj0 - 3; wj0 = wj0 < 0 ? 0 : (wj0 > IMW - WIN ? IMW - WIN : wj0);
    int tid = threadIdx.x;
    const size_t hbase = (size_t)head * NPIX;

    for (int c = tid; c < 784; c += 256) {
        int i = c / 56, part = c - i * 56;
        int n = i * WIN + (part >> 2);
        int d0 = (part & 3) * 8;
        size_t goff = (hbase + (size_t)(wi0 + i) * IMW + wj0) * 32 + part * 8;
        short8 kk = *(const short8*)(kbuf + goff);
        short8 vv = *(const short8*)(vbuf + goff);
        *(short8*)&Ks[n * 40 + d0] = kk;
        union { short8 v; unsigned short u[8]; } cu; cu.v = vv;
        #pragma unroll
        for (int e = 0; e < 8; e++)
            *(unsigned short*)&Vt[(d0 + e) * 228 + n] = cu.u[e];
    }
    for (int c = tid; c < 896; c += 256) {
        int d = c / 28, k = 196 + (c - d * 28);
        *(unsigned short*)&Vt[d * 228 + k] = 0;
    }
    if (tid < 169) rpbs[tid] = rpb[head * 169 + tid];

    int w = tid >> 6, l = tid & 63;
    int cl = l & 15, ch = l >> 4;

    int p0 = w * 16 + cl;
    int qpi = ti0 + (p0 >> 3), qpj = tj0 + (p0 & 7);
    short8 afq = *(const short8*)(qbuf + (hbase + (size_t)(qpi * IMW + qpj)) * 32 + ch * 8);

    int pi_r[4], pj_r[4], si_r[4], sj_r[4];
    #pragma unroll
    for (int r = 0; r < 4; r++) {
        int qr = w * 16 + ch * 4 + r;
        int pi = ti0 + (qr >> 3), pj = tj0 + (qr & 7);
        int si = pi - 3; si = si < 0 ? 0 : (si > IMH - KSZ ? IMH - KSZ : si);
        int sj = pj - 3; sj = sj < 0 ? 0 : (sj > IMW - KSZ ? IMW - KSZ : sj);
        pi_r[r] = pi; pj_r[r] = pj; si_r[r] = si; sj_r[r] = sj;
    }

    __syncthreads();

    f32x4 sc[13] = {};
    #pragma unroll
    for (int t = 0; t < 13; t++) {
        short8 bk = *(const short8*)&Ks[(t * 16 + cl) * 40 + ch * 8];
        sc[t] = __builtin_amdgcn_mfma_f32_16x16x32_bf16(afq, bk, sc[t], 0, 0, 0);
    }

    float mrow[4] = {-1e30f, -1e30f, -1e30f, -1e30f};
    #pragma unroll
    for (int t = 0; t < 13; t++) {
        int n = t * 16 + cl;
        int ni = (n * 9363) >> 17;
        int nj = n - ni * 14;
        int gi = wi0 + ni, gj = wj0 + nj;
        #pragma unroll
        for (int r = 0; r < 4; r++) {
            int di = gi - si_r[r], dj = gj - sj_r[r];
            bool valid = ((unsigned)di < 7u) && ((unsigned)dj < 7u);
            int bix = (gi - pi_r[r] + 6) * 13 + (gj - pj_r[r] + 6);
            float b = rpbs[valid ? bix : 0];
            float sv = valid ? sc[t][r] + b : -1e30f;
            sc[t][r] = sv;
            mrow[r] = fmaxf(mrow[r], sv);
        }
    }
    #pragma unroll
    for (int off = 1; off <= 8; off <<= 1)
        #pragma unroll
        for (int r = 0; r < 4; r++) mrow[r] = fmaxf(mrow[r], __shfl_xor(mrow[r], off));

    float lrow[4] = {};
    #pragma unroll
    for (int t = 0; t < 13; t++) {
        #pragma unroll
        for (int r = 0; r < 4; r++) {
            float e = __expf(sc[t][r] - mrow[r]);
            sc[t][r] = e;
            lrow[r] += e;
        }
    }
    #pragma unroll
    for (int off = 1; off <= 8; off <<= 1)
        #pragma unroll
        for (int r = 0; r < 4; r++) lrow[r] += __shfl_xor(lrow[r], off);

    f32x4 o[2] = {};
    #pragma unroll
    for (int t = 0; t < 8; t++)
        #pragma unroll
        for (int r = 0; r < 4; r++)
            Ps[w][(ch * 4 + r) * 136 + t * 16 + cl] = __float2bfloat16(sc[t][r]);
    #pragma unroll
    for (int ks = 0; ks < 4; ks++) {
        short8 ap = *(const short8*)&Ps[w][cl * 136 + ks * 32 + ch * 8];
        #pragma unroll
        for (int nt = 0; nt < 2; nt++) {
            short8 bv = *(const short8*)&Vt[(nt * 16 + cl) * 228 + ks * 32 + ch * 8];
            o[nt] = __builtin_amdgcn_mfma_f32_16x16x32_bf16(ap, bv, o[nt], 0, 0, 0);
        }
    }
    #pragma unroll
    for (int t = 8; t < 13; t++)
        #pragma unroll
        for (int r = 0; r < 4; r++)
            Ps[w][(ch * 4 + r) * 136 + (t - 8) * 16 + cl] = __float2bfloat16(sc[t][r]);
    #pragma unroll
    for (int r = 0; r < 4; r++)
        *(unsigned short*)&Ps[w][(ch * 4 + r) * 136 + 80 + cl] = 0;
    #pragma unroll
    for (int ks = 0; ks < 3; ks++) {
        short8 ap = *(const short8*)&Ps[w][cl * 136 + ks * 32 + ch * 8];
        #pragma unroll
        for (int nt = 0; nt < 2; nt++) {
            short8 bv = *(const short8*)&Vt[(nt * 16 + cl) * 228 + (4 + ks) * 32 + ch * 8];
            o[nt] = __builtin_amdgcn_mfma_f32_16x16x32_bf16(ap, bv, o[nt], 0, 0, 0);
        }
    }

    #pragma unroll
    for (int r = 0; r < 4; r++) {
        int qr = w * 16 + ch * 4 + r;
        int pi = ti0 + (qr >> 3), pj = tj0 + (qr & 7);
        float rl = 1.f / lrow[r];
        __hip_bfloat16* op = out + (size_t)(pi * IMW + pj) * DIM + head * HD;
        op[cl]      = __float2bfloat16(o[0][r] * rl);
        op[16 + cl] = __float2bfloat16(o[1][r] * rl);
    }
}

extern "C" void kernel_launch(void* const* d_in, const int* in_sizes, int n_in,
                              void* d_out, int out_size, void* d_ws, size_t ws_size,
                              hipStream_t stream)
{
    const float* x      = (const float*)d_in[0];
    const float* qkv_w  = (const float*)d_in[1];
    const float* qkv_b  = (const float*)d_in[2];
    const float* proj_w = (const float*)d_in[3];
    const float* proj_b = (const float*)d_in[4];
    const float* rpb    = (const float*)d_in[5];
    const float* ln1_w  = (const float*)d_in[6];
    const float* ln1_b  = (const float*)d_in[7];
    const float* ln2_w  = (const float*)d_in[8];
    const float* ln2_b  = (const float*)d_in[9];
    const float* fc1_w  = (const float*)d_in[10];
    const float* fc1_b  = (const float*)d_in[11];
    const float* fc2_w  = (const float*)d_in[12];
    const float* fc2_b  = (const float*)d_in[13];
    const float* gamma1 = (const float*)d_in[14];
    const float* gamma2 = (const float*)d_in[15];
    const int*   quality= (const int*)d_in[16];
    float* out = (float*)d_out;

    char* ws = (char*)d_ws;
    __hip_bfloat16* qbuf   = (__hip_bfloat16*)ws;                // 6.29 MB
    __hip_bfloat16* kbuf   = (__hip_bfloat16*)(ws + 12582912);   // 6.29 MB
    __hip_bfloat16* vbuf   = (__hip_bfloat16*)(ws + 18874368);   // 6.29 MB
    __hip_bfloat16* attn_b = (__hip_bfloat16*)(ws + 44040192);
    __hip_bfloat16* wq     = (__hip_bfloat16*)(ws + 50331648);
    __hip_bfloat16* wp     = (__hip_bfloat16*)(ws + 50552832);
    __hip_bfloat16* wf1    = (__hip_bfloat16*)(ws + 50626560);
    __hip_bfloat16* wf2    = (__hip_bfloat16*)(ws + 50921472);

    // 0. qkv weights->bf16 (108 blocks)
    cvt_w<<<108, 256, 0, stream>>>(qkv_w, wq);
    // 1. QKV GEMM with fused LN1 (q written as bf16)
    qkv_ln_gemm<<<512, 256, 0, stream>>>(
        x, ln1_w, ln1_b, wq, qkv_b, qbuf, kbuf, vbuf);
    // 2. MFMA neighborhood attention, 3 blocks/CU (+324 piggyback cvt blocks)
    attn_mfma<<<dim3(256 + 324, NHD), 256, 0, stream>>>(
        qbuf, kbuf, vbuf, rpb, attn_b, proj_w, fc1_w, fc2_w, wp, wf1, wf2);
    // 3. fused tail v3 (interleaved FC1/FC2)
    tail_fused<<<256, 1024, 0, stream>>>(
        attn_b, wp, proj_b, x, gamma1, ln2_w, ln2_b,
        wf1, fc1_b, wf2, fc2_b, gamma2, quality, out);
}